// Round 26
// baseline (270.269 us; speedup 1.0000x reference)
//
#include <hip/hip_runtime.h>
#include <hip/hip_fp16.h>
#include <math.h>

#define BATCH 128
#define NTOK  343
#define NPAD  352
#define CDIM  384
#define NH    12
#define DH    32
#define NWIN  32
#define MTOK  (BATCH*NTOK)   // 43904
#define NN    (NTOK*NTOK)    // 117649
#define QKVF  (3*CDIM)       // 1152
#define KSTR  40             // attn K LDS row stride (halves)
#define VSTR  360
#define PSTR  108            // P stride: 54 dwords; b64-aligned; 2-way bank (free)
#define BTI   22             // bias_sw i-tiles
#define BJT   22             // bias_sw j-tiles
#define BSWT  (BTI*BJT*256)  // elements per head/window in fragment tables (123904)

#define LOG2E 1.4426950408889634f

typedef float    f32x4 __attribute__((ext_vector_type(4)));
typedef _Float16 half8 __attribute__((ext_vector_type(8)));
typedef _Float16 half4 __attribute__((ext_vector_type(4)));

#define LDS_K   (NPAD*KSTR)                 // 14080 halves = 28160 B
#define LDS_V   (DH*VSTR)                   // 11520 halves = 23040 B
#define LDS_P   (16*PSTR)                   // 1728 halves  = 3456 B per wave
#define LDS_TOT (LDS_K + LDS_V + 8*LDS_P)   // 39424 halves = 78848 B (2 blocks/CU)

// prep_k grid sections
#define NX    (MTOK*CDIM)          // 16,859,136
#define NWQ   (QKVF*CDIM)          // 442,368
#define NWP   (CDIM*CDIM)          // 147,456
#define NXB   (NX/2048)            // 8232 blocks
#define NWQB  (NWQ/2048)           // 216
#define NWPB  (NWP/2048)           // 72
#define NMSB  (NWIN*(BSWT/256))    // 15488  (mask_sw: 484 blocks per window)
#define NBSB  ((BSWT+255)/256)     // 484
#define PREPB (NXB+NWQB+NWPB+NMSB+NBSB)  // 24492

// async global->LDS, 16B per lane; LDS dest = wave-uniform base + lane*16
__device__ __forceinline__ void gl2lds16(const __half* g, __half* l) {
  __builtin_amdgcn_global_load_lds(
      (const __attribute__((address_space(1))) void*)g,
      (__attribute__((address_space(3))) void*)l,
      16, 0, 0);
}

__device__ __forceinline__ void cvt8(const float* in, __half* out, int i) {
  float4 a = *(const float4*)&in[i];
  float4 b = *(const float4*)&in[i + 4];
  half8 h;
  h[0] = (_Float16)a.x; h[1] = (_Float16)a.y; h[2] = (_Float16)a.z; h[3] = (_Float16)a.w;
  h[4] = (_Float16)b.x; h[5] = (_Float16)b.y; h[6] = (_Float16)b.z; h[7] = (_Float16)b.w;
  *(half8*)&out[i] = h;
}

// ---------------- fused prep: cvt x/wq/wp + mask fp16 table + bias gather -----
// Both tables in SWAPPED fragment order: index t=(((ti*22+jt)*4+lg)*16+lr)*4+r
// maps to (i=ti*16+lr, j=jt*16+lg*4+r).
//   bias_sw[h][t] = bias*LOG2E   (pad i/j>=343 -> -1000, exp2 -> 0)
//   mask_sw[w][t] = allowed ? 0 : -100*LOG2E   (pad -> 0; bias pad handles it)
__global__ __launch_bounds__(256) void prep_k(
    const float* __restrict__ x,      __half* __restrict__ xh,
    const float* __restrict__ wq,     __half* __restrict__ wqh,
    const float* __restrict__ wp,     __half* __restrict__ wph,
    const float* __restrict__ mask,   __half* __restrict__ mask_sw,
    const int* __restrict__ rel_index, const float* __restrict__ table,
    __half* __restrict__ bias_sw) {
  const int blk = blockIdx.x;
  const int tid = threadIdx.x;

  if (blk < NXB) {                                   // cvt x -> fp16
    int i = (blk * 256 + tid) * 8;
    if (i < NX) cvt8(x, xh, i);
    return;
  }
  if (blk < NXB + NWQB) {                            // cvt w_qkv -> fp16
    int i = ((blk - NXB) * 256 + tid) * 8;
    if (i < NWQ) cvt8(wq, wqh, i);
    return;
  }
  if (blk < NXB + NWQB + NWPB) {                     // cvt w_proj -> fp16
    int i = ((blk - NXB - NWQB) * 256 + tid) * 8;
    if (i < NWP) cvt8(wp, wph, i);
    return;
  }
  if (blk < NXB + NWQB + NWPB + NMSB) {              // mask_sw fp16 table
    int bl = blk - NXB - NWQB - NWPB;
    int w  = bl / (BSWT / 256);
    int t  = (bl % (BSWT / 256)) * 256 + tid;
    int r  = t & 3;
    int lr = (t >> 2) & 15;
    int lg = (t >> 6) & 3;
    int jt = (t >> 8) % BJT;
    int ti = (t >> 8) / BJT;
    int i = ti * 16 + lr;
    int j = jt * 16 + lg * 4 + r;
    float v = 0.f;
    if (i < NTOK && j < NTOK && mask[(size_t)w * NN + i * NTOK + j] != 0.0f)
      v = -100.f * LOG2E;
    mask_sw[(size_t)w * BSWT + t] = __float2half(v);
    return;
  }
  {                                                  // bias gather (swapped order)
    int t = (blk - NXB - NWQB - NWPB - NMSB) * 256 + tid;
    if (t >= BSWT) return;
    int r  = t & 3;
    int lr = (t >> 2) & 15;
    int lg = (t >> 6) & 3;
    int jt = (t >> 8) % BJT;
    int ti = (t >> 8) / BJT;
    int i = ti * 16 + lr;              // query from lr (swapped)
    int j = jt * 16 + lg * 4 + r;      // key from lg,r (swapped)
    if (i < NTOK && j < NTOK) {
      int idx = rel_index[i * NTOK + j];
#pragma unroll
      for (int hh = 0; hh < NH; ++hh)
        bias_sw[(size_t)hh * BSWT + t] = __float2half(table[idx * NH + hh] * LOG2E);
    } else {
      __half pad = __float2half(-1000.0f);
#pragma unroll
      for (int hh = 0; hh < NH; ++hh)
        bias_sw[(size_t)hh * BSWT + t] = pad;
    }
  }
}

// ---------------- MFMA GEMM (all-fp16, gl2lds staging, BK=64, XCD swizzle) ----
// EPI 0: packed qkv fp16 store (q scaled by 32^-0.5 * LOG2E -> log2 units).
// EPI 1: fp32 out = acc + bias.
template<int EPI>
__global__ __launch_bounds__(256) void gemm_mfma_k(
    const __half* __restrict__ Ah, const __half* __restrict__ Bh,
    const float* __restrict__ bias, void* __restrict__ Cv) {
  __shared__ __half As[1024 * 8];   // [kg 8][row 128][8]  = 16 KB
  __shared__ __half Bs[1024 * 8];
  const int tid  = threadIdx.x;
  const int lane = tid & 63, wave = tid >> 6;
  const int lr = lane & 15, lg = lane >> 4;
  const int wr = wave >> 1, wc = wave & 1;

  // XCD-bijective swizzle of the flat block id (m204)
  const int nwg = gridDim.x * gridDim.y;
  const int flat = blockIdx.y * gridDim.x + blockIdx.x;
  const int q = nwg >> 3, rr = nwg & 7;
  const int xcd = flat & 7, lid = flat >> 3;
  const int swz = (xcd < rr ? xcd * (q + 1) : rr * (q + 1) + (xcd - rr) * q) + lid;
  const int n0 = (swz % gridDim.x) * 128;
  const int m0 = (swz / gridDim.x) * 128;
  const int KD = 384;

  f32x4 acc[4][4];
#pragma unroll
  for (int i = 0; i < 4; ++i)
#pragma unroll
    for (int j = 0; j < 4; ++j) acc[i][j] = (f32x4){0.f, 0.f, 0.f, 0.f};

  for (int k0 = 0; k0 < KD; k0 += 64) {
#pragma unroll
    for (int i = 0; i < 4; ++i) {
      int cb = wave * 256 + i * 64;          // wave-uniform chunk base
      int c  = cb + lane;
      int row = c & 127, kg = c >> 7;        // kg 0..7
      gl2lds16(&Ah[(size_t)(m0 + row) * KD + k0 + kg * 8], &As[cb * 8]);
      gl2lds16(&Bh[(size_t)(n0 + row) * KD + k0 + kg * 8], &Bs[cb * 8]);
    }
    __syncthreads();

#pragma unroll
    for (int kk = 0; kk < 2; ++kk) {         // two K=32 halves
      const int kg = lg + kk * 4;
      half8 af[4], bf[4];
#pragma unroll
      for (int t = 0; t < 4; ++t) {
        af[t] = *(const half8*)&As[(kg * 128 + wr * 64 + t * 16 + lr) * 8];
        bf[t] = *(const half8*)&Bs[(kg * 128 + wc * 64 + t * 16 + lr) * 8];
      }
#pragma unroll
      for (int mi = 0; mi < 4; ++mi)
#pragma unroll
        for (int ni = 0; ni < 4; ++ni)
          acc[mi][ni] = __builtin_amdgcn_mfma_f32_16x16x32_f16(af[mi], bf[ni], acc[mi][ni], 0, 0, 0);
    }
    __syncthreads();
  }

#pragma unroll
  for (int mi = 0; mi < 4; ++mi) {
#pragma unroll
    for (int r = 0; r < 4; ++r) {
      int m = m0 + wr * 64 + mi * 16 + lg * 4 + r;
#pragma unroll
      for (int ni = 0; ni < 4; ++ni) {
        int f = n0 + wc * 64 + ni * 16 + lr;
        float v = acc[mi][ni][r];
        if (EPI == 0) {
          if (f < CDIM) v *= (0.17677669529663687f * LOG2E);   // q scale, log2 units
          ((__half*)Cv)[(size_t)m * QKVF + f] = __float2half(v);
        } else {
          ((float*)Cv)[(size_t)m * CDIM + f] = v + bias[f];
        }
      }
    }
  }
}

// ---------------- MFMA attention: 1 block per (b,h), 8 waves ----------------
// r25 swapped-QK chunked fixed-max base; ONLY change: mask via fp16 additive
// table in fragment order (bm = bt + mt, 2 pk_adds) -- deletes the per-element
// shift/and/cndmask bit path and all mbits loads.
__global__ __launch_bounds__(512, 1) void attn_k(
    const __half* __restrict__ qkvh, const __half* __restrict__ bias_sw,
    const __half* __restrict__ mask_sw, __half* __restrict__ av) {
  extern __shared__ __half smem[];
  __half* Ks = smem;                 // [NPAD][KSTR]
  __half* Vt = smem + LDS_K;         // [DH][VSTR]
  const int tid  = threadIdx.x;
  const int wave = tid >> 6, lane = tid & 63;
  const int lr   = lane & 15, lg = lane >> 4;
  __half* Pw = smem + LDS_K + LDS_V + wave * LDS_P;  // per-wave [16][PSTR]

  const int bh = blockIdx.x;
  const int b  = bh / NH, h = bh - b * NH;
  const int w  = b & (NWIN - 1);
  const size_t tbase = (size_t)b * NTOK;
  const int hoff = h * DH;

  for (int idx = tid; idx < NPAD * 4; idx += 512) {
    int j = idx >> 2, off = (idx & 3) << 3;
    half8 val = {0,0,0,0,0,0,0,0};
    if (j < NTOK) val = *reinterpret_cast<const half8*>(&qkvh[(tbase + j) * QKVF + CDIM + hoff + off]);
    *reinterpret_cast<half8*>(&Ks[j * KSTR + off]) = val;
  }
  for (int idx = tid; idx < NPAD * 4; idx += 512) {
    int j = idx >> 2, off = (idx & 3) << 3;
    if (j < NTOK) {
      union { float4 f; __half h[8]; } u;
      u.f = *reinterpret_cast<const float4*>(&qkvh[(tbase + j) * QKVF + 2 * CDIM + hoff + off]);
#pragma unroll
      for (int uu = 0; uu < 8; ++uu) Vt[(off + uu) * VSTR + j] = u.h[uu];
    } else {
#pragma unroll
      for (int uu = 0; uu < 8; ++uu) Vt[(off + uu) * VSTR + j] = __float2half(0.f);
    }
  }
  __syncthreads();

  const __half* bias_h = bias_sw + (size_t)h * BSWT;
  const __half* mask_h = mask_sw + (size_t)w * BSWT;
  const int lgofs = lg * 64 + lr * 4;       // per-lane offset within a jt

  for (int i0 = wave * 16; i0 < NPAD; i0 += 128) {
    int qrow = min(i0 + lr, NTOK - 1);
    half8 qa = *reinterpret_cast<const half8*>(&qkvh[(tbase + qrow) * QKVF + hoff + lg * 8]);

    const __half* bias_t = bias_h + (size_t)(i0 >> 4) * (BJT * 256) + lgofs;
    const __half* mask_t = mask_h + (size_t)(i0 >> 4) * (BJT * 256) + lgofs;

    f32x4 o0 = {0.f, 0.f, 0.f, 0.f}, o1 = {0.f, 0.f, 0.f, 0.f};
    float sm = 0.f;                                   // partial over this lane's keys
    const f32x4 zf = {0.f, 0.f, 0.f, 0.f};

#pragma unroll
    for (int c = 0; c < 4; ++c) {
      const int njt = (c < 3) ? 6 : 4;   // chunk 3 covers keys 288..351
      const int nkt = (c < 3) ? 3 : 2;

      // QK^T swapped: s[jl][r] = S[key=jt*16+lg*4+r][query=i0+lr]
      f32x4 s[6];
#pragma unroll
      for (int jl_ = 0; jl_ < njt; ++jl_) {
        int jt = c * 6 + jl_;
        half8 kb = *reinterpret_cast<const half8*>(&Ks[(jt * 16 + lr) * KSTR + lg * 8]);
        s[jl_] = __builtin_amdgcn_mfma_f32_16x16x32_f16(kb, qa, zf, 0, 0, 0);
      }

      // fused (bias+mask) fp16 add + fixed-max exp2 + partial-sum + b64 P-store
#pragma unroll
      for (int jl_ = 0; jl_ < njt; ++jl_) {
        int jt = c * 6 + jl_;
        half4 bt = *(const half4*)&bias_t[jt * 256];
        half4 mt = *(const half4*)&mask_t[jt * 256];
        half4 bm = bt + mt;                           // 2x v_pk_add_f16
        float p[4];
#pragma unroll
        for (int r = 0; r < 4; ++r) {
          p[r] = exp2f(s[jl_][r] + (float)bm[r]);
          sm += p[r];
        }
        half4 hv;
        hv[0] = (_Float16)p[0]; hv[1] = (_Float16)p[1];
        hv[2] = (_Float16)p[2]; hv[3] = (_Float16)p[3];
        // CHUNK-LOCAL key offset (jl_), matching the PV read below
        *(half4*)&Pw[lr * PSTR + jl_ * 16 + lg * 4] = hv;
      }
      asm volatile("s_waitcnt lgkmcnt(0)" ::: "memory");
      __builtin_amdgcn_sched_barrier(0);

      // PV for this chunk (P layout [query][chunk-local key])
#pragma unroll
      for (int ktl = 0; ktl < nkt; ++ktl) {
        int ktg = c * 3 + ktl;
        half8 pa  = *reinterpret_cast<const half8*>(&Pw[lr * PSTR + ktl * 32 + lg * 8]);
        half8 vb0 = *reinterpret_cast<const half8*>(&Vt[lr * VSTR + ktg * 32 + lg * 8]);
        half8 vb1 = *reinterpret_cast<const half8*>(&Vt[(16 + lr) * VSTR + ktg * 32 + lg * 8]);
        o0 = __builtin_amdgcn_mfma_f32_16x16x32_f16(pa, vb0, o0, 0, 0, 0);
        o1 = __builtin_amdgcn_mfma_f32_16x16x32_f16(pa, vb1, o1, 0, 0, 0);
      }
      __builtin_amdgcn_sched_barrier(0);   // keep chunk liveness separate
    }

    // row sum lives at query=i0+lr, sliced across lg: reduce over lg bits
    sm += __shfl_xor(sm, 16);
    sm += __shfl_xor(sm, 32);

    // redistribute: output row r needs sum of query i0+lg*4+r (lane lr'=lg*4+r)
#pragma unroll
    for (int r = 0; r < 4; ++r) {
      int i = i0 + lg * 4 + r;
      if (i < NTOK) {
        float smr = __shfl(sm, (lane & 48) | (lg * 4 + r));
        float inv = 1.f / smr;
        size_t ob = ((size_t)b * NTOK + i) * CDIM + hoff;
        av[ob + lr]      = __float2half(o0[r] * inv);
        av[ob + 16 + lr] = __float2half(o1[r] * inv);
      }
    }
  }
}

extern "C" void kernel_launch(void* const* d_in, const int* in_sizes, int n_in,
                              void* d_out, int out_size, void* d_ws, size_t ws_size,
                              hipStream_t stream) {
  const float* x          = (const float*)d_in[0];
  const float* mask       = (const float*)d_in[4];
  const float* w_qkv      = (const float*)d_in[6];
  const float* bias_table = (const float*)d_in[7];
  const float* w_proj     = (const float*)d_in[8];
  const float* b_proj     = (const float*)d_in[9];
  const int*   rel_index  = (const int*)d_in[10];
  float* out = (float*)d_out;

  // ws (~146.9 MB): qkvh [MTOK][1152] fp16, avb [MTOK][384] fp16 (alias xh),
  // bias_sw [12][BSWT] fp16, mask_sw [32][BSWT] fp16, wqkvh, wprojh
  __half* qkvh   = (__half*)d_ws;
  __half* avb    = qkvh + (size_t)MTOK * QKVF;
  __half* xh     = avb;                                  // alias
  __half* bias_sw = avb + (size_t)MTOK * CDIM;
  __half* mask_sw = bias_sw + (size_t)NH * BSWT;
  __half* wqkvh  = mask_sw + (size_t)NWIN * BSWT;
  __half* wprojh = wqkvh + (size_t)QKVF * CDIM;

  // fused prep: cvt x/wq/wp + mask fp16 table + bias gather in ONE launch
  prep_k<<<PREPB, 256, 0, stream>>>(x, xh, w_qkv, wqkvh, w_proj, wprojh,
                                    mask, mask_sw, rel_index, bias_table, bias_sw);

  // QKV: A = xh, B = wqkvh, C = packed qkvh (fp16, q scaled to log2 units)
  gemm_mfma_k<0><<<dim3(QKVF / 128, MTOK / 128), 256, 0, stream>>>(
      xh, wqkvh, nullptr, qkvh);

  (void)hipFuncSetAttribute((const void*)attn_k,
                            hipFuncAttributeMaxDynamicSharedMemorySize, LDS_TOT * 2);
  attn_k<<<BATCH * NH, 512, LDS_TOT * 2, stream>>>(qkvh, bias_sw, mask_sw, avb);

  // proj: A = avb (fp16), B = wprojh, C = out (fp32 + bias)
  gemm_mfma_k<1><<<dim3(CDIM / 128, MTOK / 128), 256, 0, stream>>>(
      avb, wprojh, b_proj, out);
}

// Round 27
// 253.256 us; speedup vs baseline: 1.0672x; 1.0672x over previous
//
#include <hip/hip_runtime.h>
#include <hip/hip_fp16.h>
#include <math.h>

#define BATCH 128
#define NTOK  343
#define NPAD  352
#define CDIM  384
#define NH    12
#define DH    32
#define NWIN  32
#define MTOK  (BATCH*NTOK)   // 43904
#define NN    (NTOK*NTOK)    // 117649
#define QKVF  (3*CDIM)       // 1152
#define KSTR  40             // attn K LDS row stride (halves)
#define VSTR  360
#define PSTR  108            // P stride: 54 dwords; b64-aligned; 2-way bank (free)
#define BTI   22             // fragment-table i-tiles
#define BJT   22             // fragment-table j-tiles
#define BSWT  (BTI*BJT*256)  // elements per head/window in fragment tables (123904)

#define LOG2E 1.4426950408889634f

typedef float    f32x4 __attribute__((ext_vector_type(4)));
typedef _Float16 half8 __attribute__((ext_vector_type(8)));
typedef _Float16 half4 __attribute__((ext_vector_type(4)));

#define LDS_K   (NPAD*KSTR)                 // 14080 halves = 28160 B
#define LDS_V   (DH*VSTR)                   // 11520 halves = 23040 B
#define LDS_P   (16*PSTR)                   // 1728 halves  = 3456 B per wave
#define LDS_TOT (LDS_K + LDS_V + 8*LDS_P)   // 39424 halves = 78848 B (2 blocks/CU)

// prep_k grid sections
#define NX    (MTOK*CDIM)          // 16,859,136
#define NWQ   (QKVF*CDIM)          // 442,368
#define NWP   (CDIM*CDIM)          // 147,456
#define NXB   (NX/2048)            // 8232 blocks
#define NWQB  (NWQ/2048)           // 216
#define NWPB  (NWP/2048)           // 72
#define NMSB  (NWIN*(BSWT/256))    // 15488  (mask_sw: 484 tiles per window)
#define NBSB  ((BSWT+255)/256)     // 484
#define PREPB (NXB+NWQB+NWPB+NMSB+NBSB)  // 24492

// async global->LDS, 16B per lane; LDS dest = wave-uniform base + lane*16
__device__ __forceinline__ void gl2lds16(const __half* g, __half* l) {
  __builtin_amdgcn_global_load_lds(
      (const __attribute__((address_space(1))) void*)g,
      (__attribute__((address_space(3))) void*)l,
      16, 0, 0);
}

__device__ __forceinline__ void cvt8(const float* in, __half* out, int i) {
  float4 a = *(const float4*)&in[i];
  float4 b = *(const float4*)&in[i + 4];
  half8 h;
  h[0] = (_Float16)a.x; h[1] = (_Float16)a.y; h[2] = (_Float16)a.z; h[3] = (_Float16)a.w;
  h[4] = (_Float16)b.x; h[5] = (_Float16)b.y; h[6] = (_Float16)b.z; h[7] = (_Float16)b.w;
  *(half8*)&out[i] = h;
}

// ---------------- fused prep: cvt x/wq/wp + mask fp16 table + bias gather -----
// Both tables in SWAPPED fragment order: index t=(((ti*22+jt)*4+lg)*16+lr)*4+r
// maps to (i=ti*16+lr, j=jt*16+lg*4+r).
//   bias_sw[h][t] = bias*LOG2E   (pad i/j>=343 -> -1000, exp2 -> 0)
//   mask_sw[w][t] = allowed ? 0 : -100*LOG2E
// mask_sw section: block = one (w,ti,jt) tile; lanes 0-15 read 16 CONSECUTIVE
// floats of a mask row (coalesced 64-B segments), write permuted t in-tile.
__global__ __launch_bounds__(256) void prep_k(
    const float* __restrict__ x,      __half* __restrict__ xh,
    const float* __restrict__ wq,     __half* __restrict__ wqh,
    const float* __restrict__ wp,     __half* __restrict__ wph,
    const float* __restrict__ mask,   __half* __restrict__ mask_sw,
    const int* __restrict__ rel_index, const float* __restrict__ table,
    __half* __restrict__ bias_sw) {
  const int blk = blockIdx.x;
  const int tid = threadIdx.x;

  if (blk < NXB) {                                   // cvt x -> fp16
    int i = (blk * 256 + tid) * 8;
    if (i < NX) cvt8(x, xh, i);
    return;
  }
  if (blk < NXB + NWQB) {                            // cvt w_qkv -> fp16
    int i = ((blk - NXB) * 256 + tid) * 8;
    if (i < NWQ) cvt8(wq, wqh, i);
    return;
  }
  if (blk < NXB + NWQB + NWPB) {                     // cvt w_proj -> fp16
    int i = ((blk - NXB - NWQB) * 256 + tid) * 8;
    if (i < NWP) cvt8(wp, wph, i);
    return;
  }
  if (blk < NXB + NWQB + NWPB + NMSB) {              // mask_sw fp16 table
    int bl = blk - NXB - NWQB - NWPB;
    int w  = bl / (BSWT / 256);
    int tj = bl % (BSWT / 256);      // tile index = ti*BJT + jt
    int li = tid >> 4;               // i within tile (0..15)
    int lj = tid & 15;               // j within tile (0..15) -> coalesced read
    int i = (tj / BJT) * 16 + li;
    int j = (tj % BJT) * 16 + lj;
    float v = 0.f;
    if (i < NTOK && j < NTOK && mask[(size_t)w * NN + (size_t)i * NTOK + j] != 0.0f)
      v = -100.f * LOG2E;
    int t = ((tj * 4 + (lj >> 2)) * 16 + li) * 4 + (lj & 3);
    mask_sw[(size_t)w * BSWT + t] = __float2half(v);
    return;
  }
  {                                                  // bias gather (swapped order)
    int t = (blk - NXB - NWQB - NWPB - NMSB) * 256 + tid;
    if (t >= BSWT) return;
    int r  = t & 3;
    int lr = (t >> 2) & 15;
    int lg = (t >> 6) & 3;
    int jt = (t >> 8) % BJT;
    int ti = (t >> 8) / BJT;
    int i = ti * 16 + lr;              // query from lr (swapped)
    int j = jt * 16 + lg * 4 + r;      // key from lg,r (swapped)
    if (i < NTOK && j < NTOK) {
      int idx = rel_index[i * NTOK + j];
#pragma unroll
      for (int hh = 0; hh < NH; ++hh)
        bias_sw[(size_t)hh * BSWT + t] = __float2half(table[idx * NH + hh] * LOG2E);
    } else {
      __half pad = __float2half(-1000.0f);
#pragma unroll
      for (int hh = 0; hh < NH; ++hh)
        bias_sw[(size_t)hh * BSWT + t] = pad;
    }
  }
}

// ---------------- MFMA GEMM (all-fp16, gl2lds staging, BK=64, XCD swizzle) ----
// EPI 0: packed qkv fp16 store (q scaled by 32^-0.5 * LOG2E -> log2 units).
// EPI 1: fp32 out = acc + bias.
template<int EPI>
__global__ __launch_bounds__(256) void gemm_mfma_k(
    const __half* __restrict__ Ah, const __half* __restrict__ Bh,
    const float* __restrict__ bias, void* __restrict__ Cv) {
  __shared__ __half As[1024 * 8];   // [kg 8][row 128][8]  = 16 KB
  __shared__ __half Bs[1024 * 8];
  const int tid  = threadIdx.x;
  const int lane = tid & 63, wave = tid >> 6;
  const int lr = lane & 15, lg = lane >> 4;
  const int wr = wave >> 1, wc = wave & 1;

  // XCD-bijective swizzle of the flat block id (m204)
  const int nwg = gridDim.x * gridDim.y;
  const int flat = blockIdx.y * gridDim.x + blockIdx.x;
  const int q = nwg >> 3, rr = nwg & 7;
  const int xcd = flat & 7, lid = flat >> 3;
  const int swz = (xcd < rr ? xcd * (q + 1) : rr * (q + 1) + (xcd - rr) * q) + lid;
  const int n0 = (swz % gridDim.x) * 128;
  const int m0 = (swz / gridDim.x) * 128;
  const int KD = 384;

  f32x4 acc[4][4];
#pragma unroll
  for (int i = 0; i < 4; ++i)
#pragma unroll
    for (int j = 0; j < 4; ++j) acc[i][j] = (f32x4){0.f, 0.f, 0.f, 0.f};

  for (int k0 = 0; k0 < KD; k0 += 64) {
#pragma unroll
    for (int i = 0; i < 4; ++i) {
      int cb = wave * 256 + i * 64;          // wave-uniform chunk base
      int c  = cb + lane;
      int row = c & 127, kg = c >> 7;        // kg 0..7
      gl2lds16(&Ah[(size_t)(m0 + row) * KD + k0 + kg * 8], &As[cb * 8]);
      gl2lds16(&Bh[(size_t)(n0 + row) * KD + k0 + kg * 8], &Bs[cb * 8]);
    }
    __syncthreads();

#pragma unroll
    for (int kk = 0; kk < 2; ++kk) {         // two K=32 halves
      const int kg = lg + kk * 4;
      half8 af[4], bf[4];
#pragma unroll
      for (int t = 0; t < 4; ++t) {
        af[t] = *(const half8*)&As[(kg * 128 + wr * 64 + t * 16 + lr) * 8];
        bf[t] = *(const half8*)&Bs[(kg * 128 + wc * 64 + t * 16 + lr) * 8];
      }
#pragma unroll
      for (int mi = 0; mi < 4; ++mi)
#pragma unroll
        for (int ni = 0; ni < 4; ++ni)
          acc[mi][ni] = __builtin_amdgcn_mfma_f32_16x16x32_f16(af[mi], bf[ni], acc[mi][ni], 0, 0, 0);
    }
    __syncthreads();
  }

#pragma unroll
  for (int mi = 0; mi < 4; ++mi) {
#pragma unroll
    for (int r = 0; r < 4; ++r) {
      int m = m0 + wr * 64 + mi * 16 + lg * 4 + r;
#pragma unroll
      for (int ni = 0; ni < 4; ++ni) {
        int f = n0 + wc * 64 + ni * 16 + lr;
        float v = acc[mi][ni][r];
        if (EPI == 0) {
          if (f < CDIM) v *= (0.17677669529663687f * LOG2E);   // q scale, log2 units
          ((__half*)Cv)[(size_t)m * QKVF + f] = __float2half(v);
        } else {
          ((float*)Cv)[(size_t)m * CDIM + f] = v + bias[f];
        }
      }
    }
  }
}

// ---------------- MFMA attention: 1 block per (b,h), 8 waves ----------------
// r26 inner loop byte-identical (swapped-QK, chunked fixed-max, fp16 mask add).
// NEW: window-grouped XCD placement -- physical chunk of 192 blocks per XCD
// covers only 4 windows (4x242KB mask + 2.9MB bias fits 4MB L2).
__global__ __launch_bounds__(512, 1) void attn_k(
    const __half* __restrict__ qkvh, const __half* __restrict__ bias_sw,
    const __half* __restrict__ mask_sw, __half* __restrict__ av) {
  extern __shared__ __half smem[];
  __half* Ks = smem;                 // [NPAD][KSTR]
  __half* Vt = smem + LDS_K;         // [DH][VSTR]
  const int tid  = threadIdx.x;
  const int wave = tid >> 6, lane = tid & 63;
  const int lr   = lane & 15, lg = lane >> 4;
  __half* Pw = smem + LDS_K + LDS_V + wave * LDS_P;  // per-wave [16][PSTR]

  // window-grouped relabel: XCD chunk (flat&7)*192 + flat>>3; logical order
  // l = w*48 + (b>>5)*12 + h  (bijective on 1536 since 1536%8==0)
  const int flat = blockIdx.x;
  const int swzb = (flat & 7) * 192 + (flat >> 3);
  const int w   = swzb / 48;
  const int rem = swzb % 48;
  const int b   = (rem / 12) * NWIN + w;
  const int h   = rem % 12;
  const size_t tbase = (size_t)b * NTOK;
  const int hoff = h * DH;

  for (int idx = tid; idx < NPAD * 4; idx += 512) {
    int j = idx >> 2, off = (idx & 3) << 3;
    half8 val = {0,0,0,0,0,0,0,0};
    if (j < NTOK) val = *reinterpret_cast<const half8*>(&qkvh[(tbase + j) * QKVF + CDIM + hoff + off]);
    *reinterpret_cast<half8*>(&Ks[j * KSTR + off]) = val;
  }
  for (int idx = tid; idx < NPAD * 4; idx += 512) {
    int j = idx >> 2, off = (idx & 3) << 3;
    if (j < NTOK) {
      union { float4 f; __half h[8]; } u;
      u.f = *reinterpret_cast<const float4*>(&qkvh[(tbase + j) * QKVF + 2 * CDIM + hoff + off]);
#pragma unroll
      for (int uu = 0; uu < 8; ++uu) Vt[(off + uu) * VSTR + j] = u.h[uu];
    } else {
#pragma unroll
      for (int uu = 0; uu < 8; ++uu) Vt[(off + uu) * VSTR + j] = __float2half(0.f);
    }
  }
  __syncthreads();

  const __half* bias_h = bias_sw + (size_t)h * BSWT;
  const __half* mask_h = mask_sw + (size_t)w * BSWT;
  const int lgofs = lg * 64 + lr * 4;       // per-lane offset within a jt

  for (int i0 = wave * 16; i0 < NPAD; i0 += 128) {
    int qrow = min(i0 + lr, NTOK - 1);
    half8 qa = *reinterpret_cast<const half8*>(&qkvh[(tbase + qrow) * QKVF + hoff + lg * 8]);

    const __half* bias_t = bias_h + (size_t)(i0 >> 4) * (BJT * 256) + lgofs;
    const __half* mask_t = mask_h + (size_t)(i0 >> 4) * (BJT * 256) + lgofs;

    f32x4 o0 = {0.f, 0.f, 0.f, 0.f}, o1 = {0.f, 0.f, 0.f, 0.f};
    float sm = 0.f;                                   // partial over this lane's keys
    const f32x4 zf = {0.f, 0.f, 0.f, 0.f};

#pragma unroll
    for (int c = 0; c < 4; ++c) {
      const int njt = (c < 3) ? 6 : 4;   // chunk 3 covers keys 288..351
      const int nkt = (c < 3) ? 3 : 2;

      // QK^T swapped: s[jl][r] = S[key=jt*16+lg*4+r][query=i0+lr]
      f32x4 s[6];
#pragma unroll
      for (int jl_ = 0; jl_ < njt; ++jl_) {
        int jt = c * 6 + jl_;
        half8 kb = *reinterpret_cast<const half8*>(&Ks[(jt * 16 + lr) * KSTR + lg * 8]);
        s[jl_] = __builtin_amdgcn_mfma_f32_16x16x32_f16(kb, qa, zf, 0, 0, 0);
      }

      // fused (bias+mask) fp16 add + fixed-max exp2 + partial-sum + b64 P-store
#pragma unroll
      for (int jl_ = 0; jl_ < njt; ++jl_) {
        int jt = c * 6 + jl_;
        half4 bt = *(const half4*)&bias_t[jt * 256];
        half4 mt = *(const half4*)&mask_t[jt * 256];
        half4 bm = bt + mt;                           // 2x v_pk_add_f16
        float p[4];
#pragma unroll
        for (int r = 0; r < 4; ++r) {
          p[r] = exp2f(s[jl_][r] + (float)bm[r]);
          sm += p[r];
        }
        half4 hv;
        hv[0] = (_Float16)p[0]; hv[1] = (_Float16)p[1];
        hv[2] = (_Float16)p[2]; hv[3] = (_Float16)p[3];
        // CHUNK-LOCAL key offset (jl_), matching the PV read below
        *(half4*)&Pw[lr * PSTR + jl_ * 16 + lg * 4] = hv;
      }
      asm volatile("s_waitcnt lgkmcnt(0)" ::: "memory");
      __builtin_amdgcn_sched_barrier(0);

      // PV for this chunk (P layout [query][chunk-local key])
#pragma unroll
      for (int ktl = 0; ktl < nkt; ++ktl) {
        int ktg = c * 3 + ktl;
        half8 pa  = *reinterpret_cast<const half8*>(&Pw[lr * PSTR + ktl * 32 + lg * 8]);
        half8 vb0 = *reinterpret_cast<const half8*>(&Vt[lr * VSTR + ktg * 32 + lg * 8]);
        half8 vb1 = *reinterpret_cast<const half8*>(&Vt[(16 + lr) * VSTR + ktg * 32 + lg * 8]);
        o0 = __builtin_amdgcn_mfma_f32_16x16x32_f16(pa, vb0, o0, 0, 0, 0);
        o1 = __builtin_amdgcn_mfma_f32_16x16x32_f16(pa, vb1, o1, 0, 0, 0);
      }
      __builtin_amdgcn_sched_barrier(0);   // keep chunk liveness separate
    }

    // row sum lives at query=i0+lr, sliced across lg: reduce over lg bits
    sm += __shfl_xor(sm, 16);
    sm += __shfl_xor(sm, 32);

    // redistribute: output row r needs sum of query i0+lg*4+r (lane lr'=lg*4+r)
#pragma unroll
    for (int r = 0; r < 4; ++r) {
      int i = i0 + lg * 4 + r;
      if (i < NTOK) {
        float smr = __shfl(sm, (lane & 48) | (lg * 4 + r));
        float inv = 1.f / smr;
        size_t ob = ((size_t)b * NTOK + i) * CDIM + hoff;
        av[ob + lr]      = __float2half(o0[r] * inv);
        av[ob + 16 + lr] = __float2half(o1[r] * inv);
      }
    }
  }
}

extern "C" void kernel_launch(void* const* d_in, const int* in_sizes, int n_in,
                              void* d_out, int out_size, void* d_ws, size_t ws_size,
                              hipStream_t stream) {
  const float* x          = (const float*)d_in[0];
  const float* mask       = (const float*)d_in[4];
  const float* w_qkv      = (const float*)d_in[6];
  const float* bias_table = (const float*)d_in[7];
  const float* w_proj     = (const float*)d_in[8];
  const float* b_proj     = (const float*)d_in[9];
  const int*   rel_index  = (const int*)d_in[10];
  float* out = (float*)d_out;

  // ws (~146.9 MB): qkvh [MTOK][1152] fp16, avb [MTOK][384] fp16 (alias xh),
  // bias_sw [12][BSWT] fp16, mask_sw [32][BSWT] fp16, wqkvh, wprojh
  __half* qkvh   = (__half*)d_ws;
  __half* avb    = qkvh + (size_t)MTOK * QKVF;
  __half* xh     = avb;                                  // alias
  __half* bias_sw = avb + (size_t)MTOK * CDIM;
  __half* mask_sw = bias_sw + (size_t)NH * BSWT;
  __half* wqkvh  = mask_sw + (size_t)NWIN * BSWT;
  __half* wprojh = wqkvh + (size_t)QKVF * CDIM;

  // fused prep: cvt x/wq/wp + mask fp16 table + bias gather in ONE launch
  prep_k<<<PREPB, 256, 0, stream>>>(x, xh, w_qkv, wqkvh, w_proj, wprojh,
                                    mask, mask_sw, rel_index, bias_table, bias_sw);

  // QKV: A = xh, B = wqkvh, C = packed qkvh (fp16, q scaled to log2 units)
  gemm_mfma_k<0><<<dim3(QKVF / 128, MTOK / 128), 256, 0, stream>>>(
      xh, wqkvh, nullptr, qkvh);

  (void)hipFuncSetAttribute((const void*)attn_k,
                            hipFuncAttributeMaxDynamicSharedMemorySize, LDS_TOT * 2);
  attn_k<<<BATCH * NH, 512, LDS_TOT * 2, stream>>>(qkvh, bias_sw, mask_sw, avb);

  // proj: A = avb (fp16), B = wprojh, C = out (fp32 + bias)
  gemm_mfma_k<1><<<dim3(CDIM / 128, MTOK / 128), 256, 0, stream>>>(
      avb, wprojh, b_proj, out);
}